// Round 3
// baseline (96.905 us; speedup 1.0000x reference)
//
#include <hip/hip_runtime.h>
#include <math.h>

// Problem dims (fixed by reference setup_inputs)
#define B 2
#define C 128
#define H 128
#define W 256
#define K 20
#define HW (H * W)

// ---------------- Kernel A: prep ----------------
// blocks 0..8191: rn[b,h,c] = 1/max(||feats[b,c,h,:]||_2, eps)  (one wave per row)
// block 8192:     pn_ws[kg][c*5+j] = protos[k,c]/max(||protos[k,:]||,eps), k=kg*5+j
//                 ppsum_ws[k] = sum_c pn[k,c]^2 (exact, fp32)
__global__ __launch_bounds__(256) void isomax_prep(
    const float* __restrict__ feats, const float* __restrict__ protos,
    float* __restrict__ rn_ws, float* __restrict__ pn_ws, float* __restrict__ ppsum_ws)
{
    const int tid = threadIdx.x, wave = tid >> 6, lane = tid & 63;
    const int blk = blockIdx.x;

    if (blk < 8192) {
        const int r = blk * 4 + wave;  // row id = (b*C + c)*H + h
        const float4 v = ((const float4*)(feats + (size_t)r * W))[lane];
        float ss = fmaf(v.x, v.x, fmaf(v.y, v.y, fmaf(v.z, v.z, v.w * v.w)));
        #pragma unroll
        for (int off = 32; off > 0; off >>= 1) ss += __shfl_xor(ss, off, 64);
        if (lane == 0) {
            const int h  = r & (H - 1);
            const int bc = r >> 7;          // r / H
            const int c  = bc & (C - 1);
            const int b  = bc >> 7;         // bc / C
            rn_ws[(b * H + h) * C + c] = 1.0f / fmaxf(sqrtf(ss), 1e-12f);
        }
    } else {
        __shared__ float s_rp[32];
        __shared__ float s_pp[32];
        for (int k = wave; k < K; k += 4) {
            const float* p = protos + k * C;
            float a = p[lane], bq = p[lane + 64];
            float ss = fmaf(a, a, bq * bq);
            #pragma unroll
            for (int off = 32; off > 0; off >>= 1) ss += __shfl_xor(ss, off, 64);
            if (lane == 0) {
                float n  = sqrtf(ss);
                float rp = 1.0f / fmaxf(n, 1e-12f);
                s_rp[k] = rp;
                float nn = n * rp;          // ==1 normally; exact ratio if n<eps
                s_pp[k] = nn * nn;
            }
        }
        __syncthreads();
        for (int i = tid; i < C * K; i += 256) {   // 2560 values
            const int kg  = i / 640;
            const int rem = i - kg * 640;
            const int c   = rem / 5;
            const int j   = rem - c * 5;
            const int k   = kg * 5 + j;
            pn_ws[i] = protos[k * C + c] * s_rp[k];
        }
        if (tid < K) ppsum_ws[tid] = s_pp[tid];
    }
}

// ---------------- Kernel B: distances ----------------
// dist^2[k] = S + sum_c pn[k]^2 - 2*dot_k,  S = sum_c fn^2  (exact mm-form)
// Thread = (kgroup of 5 k's, w). All pn/rn accesses wave-uniform -> s_load (SGPR),
// zero LDS, zero barriers. Grid = B*H*(W/64) = 1024 blocks, 16 waves/CU.
__global__ __launch_bounds__(256, 4) void isomax_dist(
    const float* __restrict__ feats, const float* __restrict__ rn_ws,
    const float* __restrict__ pn_ws, const float* __restrict__ ppsum_ws,
    const float* __restrict__ dscale, float* __restrict__ out)
{
    const int tid = threadIdx.x;
    const int kg  = __builtin_amdgcn_readfirstlane(tid >> 6);  // wave-uniform k-group
    const int wl  = tid & 63;
    const int blk = blockIdx.x;
    const int wt  = blk & 3;
    const int bh  = blk >> 2;
    const int b   = bh >> 7;      // H = 128
    const int h   = bh & 127;
    const int w   = wt * 64 + wl;

    const float* fp = feats + ((size_t)b * C * H + h) * W + w;  // stride H*W per c
    const float* rn = rn_ws + bh * C;                           // uniform
    const float* pk = pn_ws + kg * (C * 5);                     // uniform

    float S = 0.f;
    float dacc[5] = {0.f, 0.f, 0.f, 0.f, 0.f};

    #pragma unroll 4
    for (int c0 = 0; c0 < C; c0 += 4) {
        const float4 r4 = *(const float4*)(rn + c0);            // uniform -> s_load
        float pp[20];                                           // pn for 4 c's x 5 k's
        ((float4*)pp)[0] = *(const float4*)(pk + c0 * 5 + 0);   // uniform -> s_load
        ((float4*)pp)[1] = *(const float4*)(pk + c0 * 5 + 4);
        ((float4*)pp)[2] = *(const float4*)(pk + c0 * 5 + 8);
        ((float4*)pp)[3] = *(const float4*)(pk + c0 * 5 + 12);
        ((float4*)pp)[4] = *(const float4*)(pk + c0 * 5 + 16);

        const float v0 = fp[(size_t)(c0 + 0) * HW] * r4.x;
        const float v1 = fp[(size_t)(c0 + 1) * HW] * r4.y;
        const float v2 = fp[(size_t)(c0 + 2) * HW] * r4.z;
        const float v3 = fp[(size_t)(c0 + 3) * HW] * r4.w;
        S = fmaf(v0, v0, S);
        S = fmaf(v1, v1, S);
        S = fmaf(v2, v2, S);
        S = fmaf(v3, v3, S);
        #pragma unroll
        for (int j = 0; j < 5; ++j) {
            float d = dacc[j];
            d = fmaf(v0, pp[j],      d);
            d = fmaf(v1, pp[5 + j],  d);
            d = fmaf(v2, pp[10 + j], d);
            d = fmaf(v3, pp[15 + j], d);
            dacc[j] = d;
        }
    }

    const float scale = fabsf(dscale[0]);
    const float* pps = ppsum_ws + kg * 5;                       // uniform
    float* ob = out + ((size_t)b * K * H + h) * W + w;
    #pragma unroll
    for (int j = 0; j < 5; ++j) {
        const int k = kg * 5 + j;
        float dist2 = fmaxf(fmaf(-2.f, dacc[j], S + pps[j]), 0.f);
        ob[(size_t)k * HW] = -scale * sqrtf(dist2);             // coalesced per k
    }
}

extern "C" void kernel_launch(void* const* d_in, const int* in_sizes, int n_in,
                              void* d_out, int out_size, void* d_ws, size_t ws_size,
                              hipStream_t stream) {
    const float* feats  = (const float*)d_in[0];
    const float* protos = (const float*)d_in[1];
    const float* dscale = (const float*)d_in[2];
    float* out = (float*)d_out;

    float* rn_ws    = (float*)d_ws;        // 32768 floats  [b][h][c]
    float* pn_ws    = rn_ws + 32768;       // 2560 floats   [kg][c*5+j]
    float* ppsum_ws = pn_ws + 2560;        // 20 floats

    isomax_prep<<<8193, 256, 0, stream>>>(feats, protos, rn_ws, pn_ws, ppsum_ws);
    isomax_dist<<<B * H * (W / 64), 256, 0, stream>>>(feats, rn_ws, pn_ws, ppsum_ws,
                                                      dscale, out);
}

// Round 4
// 95.419 us; speedup vs baseline: 1.0156x; 1.0156x over previous
//
#include <hip/hip_runtime.h>
#include <math.h>

// Problem dims (fixed by reference setup_inputs)
#define B 2
#define C 128
#define H 128
#define W 256
#define K 20
#define HW (H * W)

// ---------------- Kernel A: prep ----------------
// blocks 0..8191: rn[b,h,c] = 1/max(||feats[b,c,h,:]||_2, eps)  (one wave per W-row)
// block 8192:     pn_ws[k*C+c] = protos[k,c]/max(||protos[k,:]||,eps)
//                 ppsum_ws[k]  = sum_c pn[k,c]^2 (fp32)
__global__ __launch_bounds__(256) void isomax_prep(
    const float* __restrict__ feats, const float* __restrict__ protos,
    float* __restrict__ rn_ws, float* __restrict__ pn_ws, float* __restrict__ ppsum_ws)
{
    const int tid = threadIdx.x, wave = tid >> 6, lane = tid & 63;
    const int blk = blockIdx.x;

    if (blk < 8192) {
        const int r = blk * 4 + wave;  // row id = (b*C + c)*H + h
        const float4 v = ((const float4*)(feats + (size_t)r * W))[lane];
        float ss = fmaf(v.x, v.x, fmaf(v.y, v.y, fmaf(v.z, v.z, v.w * v.w)));
        #pragma unroll
        for (int off = 32; off > 0; off >>= 1) ss += __shfl_xor(ss, off, 64);
        if (lane == 0) {
            const int h  = r & (H - 1);
            const int bc = r >> 7;          // r / H
            const int c  = bc & (C - 1);
            const int b  = bc >> 7;         // bc / C
            rn_ws[(b * H + h) * C + c] = 1.0f / fmaxf(sqrtf(ss), 1e-12f);
        }
    } else {
        __shared__ float s_rp[32];
        __shared__ float s_pp[32];
        for (int k = wave; k < K; k += 4) {
            const float* p = protos + k * C;
            float a = p[lane], bq = p[lane + 64];
            float ss = fmaf(a, a, bq * bq);
            #pragma unroll
            for (int off = 32; off > 0; off >>= 1) ss += __shfl_xor(ss, off, 64);
            if (lane == 0) {
                float n  = sqrtf(ss);
                float rp = 1.0f / fmaxf(n, 1e-12f);
                s_rp[k] = rp;
                float nn = n * rp;          // ==1 normally; exact ratio if n<eps
                s_pp[k] = nn * nn;
            }
        }
        __syncthreads();
        for (int i = tid; i < C * K; i += 256) {   // plain [k][c] layout
            const int k = i >> 7;          // i / C
            pn_ws[i] = protos[i] * s_rp[k];
        }
        if (tid < K) ppsum_ws[tid] = s_pp[tid];
    }
}

// ---------------- Kernel B: distances ----------------
// Block = (b, h, whalf): 256 threads = 4 waves = 4 k-groups; lane owns 2 w (float2).
// Per-c coefficients packed per (c,kg) in one 32B LDS record (broadcast reads):
//   s_pd[c][kg] = { -2*rn[c]*pn[k,c] for k=kg*5..kg*5+4,  rn[c]^2,  pad,pad }
// dist^2[k] = S + ppsum[k] + sum_c v_c * (-2 rn_c pn_kc),  S = sum_c v_c^2 rn_c^2
__global__ __launch_bounds__(256) void isomax_dist(
    const float* __restrict__ feats, const float* __restrict__ rn_ws,
    const float* __restrict__ pn_ws, const float* __restrict__ ppsum_ws,
    const float* __restrict__ dscale, float* __restrict__ out)
{
    __shared__ __align__(16) float s_pd[C][4][8];   // 16 KB
    __shared__ float s_pp[K];

    const int tid   = threadIdx.x;
    const int blk   = blockIdx.x;
    const int whalf = blk & 1;
    const int bh    = blk >> 1;          // b*H + h
    const int b     = bh >> 7;
    const int h     = bh & 127;
    const int kg    = tid >> 6;          // wave id = k-group
    const int lane  = tid & 63;

    const float* rn = rn_ws + bh * C;

    // Fill per-block LDS coefficient table (one barrier total).
    for (int i = tid; i < C * K; i += 256) {        // 2560
        const int c  = i / K;
        const int k  = i - c * K;
        const int g  = k / 5;
        const int j  = k - g * 5;
        s_pd[c][g][j] = -2.0f * rn[c] * pn_ws[k * C + c];
    }
    for (int i = tid; i < C * 4; i += 256) {        // 512: rn^2 copies per kg
        const int c = i >> 2, g = i & 3;
        const float r = rn[c];
        s_pd[c][g][5] = r * r;
    }
    if (tid < K) s_pp[tid] = ppsum_ws[tid];
    __syncthreads();

    const int w0 = whalf * 128 + lane * 2;
    const float* fp = feats + ((size_t)(b * C) * H + h) * W + w0;

    float d0[5] = {0.f, 0.f, 0.f, 0.f, 0.f};
    float d1[5] = {0.f, 0.f, 0.f, 0.f, 0.f};
    float S0 = 0.f, S1 = 0.f;

    #pragma unroll 8
    for (int c = 0; c < C; ++c) {
        const float2 f2 = *(const float2*)(fp + (size_t)c * HW);   // 512 B / wave
        const float* pd = s_pd[c][kg];                              // broadcast
        const float p0 = pd[0], p1 = pd[1], p2 = pd[2], p3 = pd[3];
        const float p4 = pd[4], r2 = pd[5];
        S0 = fmaf(f2.x * f2.x, r2, S0);
        S1 = fmaf(f2.y * f2.y, r2, S1);
        d0[0] = fmaf(f2.x, p0, d0[0]);  d1[0] = fmaf(f2.y, p0, d1[0]);
        d0[1] = fmaf(f2.x, p1, d0[1]);  d1[1] = fmaf(f2.y, p1, d1[1]);
        d0[2] = fmaf(f2.x, p2, d0[2]);  d1[2] = fmaf(f2.y, p2, d1[2]);
        d0[3] = fmaf(f2.x, p3, d0[3]);  d1[3] = fmaf(f2.y, p3, d1[3]);
        d0[4] = fmaf(f2.x, p4, d0[4]);  d1[4] = fmaf(f2.y, p4, d1[4]);
    }

    const float scale = fabsf(dscale[0]);
    float* ob = out + ((size_t)(b * K) * H + h) * W + w0;
    #pragma unroll
    for (int j = 0; j < 5; ++j) {
        const int k = kg * 5 + j;
        const float pp = s_pp[k];
        float q0 = fmaxf(S0 + pp + d0[j], 0.f);
        float q1 = fmaxf(S1 + pp + d1[j], 0.f);
        float2 o;
        o.x = -scale * sqrtf(q0);
        o.y = -scale * sqrtf(q1);
        *(float2*)(ob + (size_t)k * HW) = o;   // 512 B contiguous per k per wave
    }
}

extern "C" void kernel_launch(void* const* d_in, const int* in_sizes, int n_in,
                              void* d_out, int out_size, void* d_ws, size_t ws_size,
                              hipStream_t stream) {
    const float* feats  = (const float*)d_in[0];
    const float* protos = (const float*)d_in[1];
    const float* dscale = (const float*)d_in[2];
    float* out = (float*)d_out;

    float* rn_ws    = (float*)d_ws;        // 32768 floats [b*H+h][c]
    float* pn_ws    = rn_ws + 32768;       // 2560 floats  [k][c]
    float* ppsum_ws = pn_ws + 2560;        // 20 floats

    isomax_prep<<<8193, 256, 0, stream>>>(feats, protos, rn_ws, pn_ws, ppsum_ws);
    isomax_dist<<<B * H * 2, 256, 0, stream>>>(feats, rn_ws, pn_ws, ppsum_ws,
                                               dscale, out);
}

// Round 5
// 91.531 us; speedup vs baseline: 1.0587x; 1.0425x over previous
//
#include <hip/hip_runtime.h>
#include <math.h>

// Problem dims (fixed by reference setup_inputs)
#define B 2
#define C 128
#define H 128
#define W 256
#define K 20
#define HW (H * W)

typedef float f32x4 __attribute__((ext_vector_type(4)));
typedef short bf16x8 __attribute__((ext_vector_type(8)));

// round-to-nearest-even fp32 -> bf16 bits (no NaN handling; inputs are finite)
__device__ __forceinline__ unsigned f2bf_bits(float x) {
    unsigned u = __float_as_uint(x);
    return (u + 0x7FFFu + ((u >> 16) & 1u)) >> 16;
}
__device__ __forceinline__ float bf_to_f(unsigned bits) {
    return __uint_as_float(bits << 16);
}

// ---------------- Kernel A: prep ----------------
// blocks 0..8191: rn[b,h,c] = 1/max(||feats[b,c,h,:]||_2, eps)   (one wave per W-row)
// block 8192:     pnf_ws  = bf16 prototypes pre-packed in MFMA B-fragment order
//                 [t][ch][lane][j] -> B[c=ch*32+(lane>>4)*8+j][k=t*16+(lane&15)], 0 if k>=20
//                 ppsum_ws[k] = sum_c bf16(pn[k,c])^2  (fp32, consistent with fragments)
__global__ __launch_bounds__(256) void isomax_prep(
    const float* __restrict__ feats, const float* __restrict__ protos,
    float* __restrict__ rn_ws, short* __restrict__ pnf_ws, float* __restrict__ ppsum_ws)
{
    const int tid = threadIdx.x, wave = tid >> 6, lane = tid & 63;
    const int blk = blockIdx.x;

    if (blk < 8192) {
        const int r = blk * 4 + wave;  // row id = (b*C + c)*H + h
        const float4 v = ((const float4*)(feats + (size_t)r * W))[lane];
        float ss = fmaf(v.x, v.x, fmaf(v.y, v.y, fmaf(v.z, v.z, v.w * v.w)));
        #pragma unroll
        for (int off = 32; off > 0; off >>= 1) ss += __shfl_xor(ss, off, 64);
        if (lane == 0) {
            const int h  = r & (H - 1);
            const int bc = r >> 7;
            const int c  = bc & (C - 1);
            const int b  = bc >> 7;
            rn_ws[(b * H + h) * C + c] = 1.0f / fmaxf(sqrtf(ss), 1e-12f);
        }
    } else {
        __shared__ float s_rp[32];
        for (int k = wave; k < K; k += 4) {
            const float* p = protos + k * C;
            float a = p[lane], bq = p[lane + 64];
            float ss = fmaf(a, a, bq * bq);
            #pragma unroll
            for (int off = 32; off > 0; off >>= 1) ss += __shfl_xor(ss, off, 64);
            if (lane == 0) s_rp[k] = 1.0f / fmaxf(sqrtf(ss), 1e-12f);
        }
        __syncthreads();
        // B-fragments: 2 n-tiles x 4 k-chunks x 64 lanes x 8 elems = 4096 bf16
        for (int i = tid; i < 4096; i += 256) {
            const int j  = i & 7;
            const int ln = (i >> 3) & 63;
            const int ch = (i >> 9) & 3;
            const int t  = i >> 11;
            const int c  = ch * 32 + ((ln >> 4) & 3) * 8 + j;
            const int k  = t * 16 + (ln & 15);
            float val = (k < K) ? protos[k * C + c] * s_rp[k] : 0.0f;
            pnf_ws[i] = (short)f2bf_bits(val);
        }
        if (tid < 32) {
            float s = 0.f;
            if (tid < K) {
                const float rp = s_rp[tid];
                for (int c = 0; c < C; ++c) {
                    float pb = bf_to_f(f2bf_bits(protos[tid * C + c] * rp));
                    s = fmaf(pb, pb, s);
                }
            }
            ppsum_ws[tid] = s;
        }
    }
}

// ---------------- Kernel B: MFMA distances ----------------
// Block = 64 consecutive w of one (b,h) row. 4 waves; wave owns m-tile = 16 w.
// s_u[c][w] fp32 (stride 68, XOR-16 swizzle on w for bank balance).
// dist^2[w,k] = S[w] + ppsum[k] - 2 * (u . pn)  via mfma_f32_16x16x32_bf16.
__global__ __launch_bounds__(256, 4) void isomax_dist(
    const float* __restrict__ feats, const float* __restrict__ rn_ws,
    const short* __restrict__ pnf_ws, const float* __restrict__ ppsum_ws,
    const float* __restrict__ dscale, float* __restrict__ out)
{
    __shared__ float s_u[C * 68];   // 34.8 KB; aliased as s_o after the last barrier
    __shared__ float s_S[64];

    const int tid  = threadIdx.x;
    const int wave = tid >> 6, lane = tid & 63;
    const int quad = lane >> 4, l16 = lane & 15;
    const int blk  = blockIdx.x;
    const int wq   = blk & 3;
    const int bh   = blk >> 2;
    const int b    = bh >> 7, h = bh & 127;
    const int w0   = wq * 64;

    // B-fragments + per-k sums (same for every block; L2/L3 broadcast)
    bf16x8 bfrag[4][2];
    #pragma unroll
    for (int t = 0; t < 2; ++t)
        #pragma unroll
        for (int ch = 0; ch < 4; ++ch)
            bfrag[ch][t] = ((const bf16x8*)pnf_ws)[(t * 4 + ch) * 64 + lane];
    const float pcol0 = ppsum_ws[l16];
    const float pcol1 = ppsum_ws[16 + l16];
    const float scale = fabsf(dscale[0]);

    // ---- Stage u = f * rn : wave covers c in [wave*32, wave*32+32), all 64 w ----
    {
        const int wl = l16 * 4;
        #pragma unroll
        for (int r = 0; r < 8; ++r) {
            const int c  = wave * 32 + quad + r * 4;
            const float rn = rn_ws[bh * C + c];
            const float4 f4 = *(const float4*)(feats + ((size_t)(b * C + c) * H + h) * W + w0 + wl);
            float4 u4;
            u4.x = f4.x * rn; u4.y = f4.y * rn; u4.z = f4.z * rn; u4.w = f4.w * rn;
            const int swz = ((c >> 3) & 1) << 4;
            *(float4*)&s_u[c * 68 + (wl ^ swz)] = u4;   // 16B-aligned, bank-balanced
        }
    }
    __syncthreads();

    // ---- K-loop: 4 chunks of 32 c; A-frag from LDS, bf16 convert in-register ----
    f32x4 acc0 = {0.f, 0.f, 0.f, 0.f}, acc1 = {0.f, 0.f, 0.f, 0.f};
    float Sp = 0.f;
    const int wm = wave * 16 + l16;          // A row m -> w-local
    const int rswz = (quad & 1) << 4;        // ((c>>3)&1) == quad&1 for c = ch*32+quad*8+j
    #pragma unroll
    for (int ch = 0; ch < 4; ++ch) {
        float uj[8];
        #pragma unroll
        for (int j = 0; j < 8; ++j)
            uj[j] = s_u[(ch * 32 + quad * 8 + j) * 68 + (wm ^ rswz)];
        bf16x8 af;
        #pragma unroll
        for (int j = 0; j < 8; ++j) {
            Sp = fmaf(uj[j], uj[j], Sp);
            af[j] = (short)f2bf_bits(uj[j]);
        }
        acc0 = __builtin_amdgcn_mfma_f32_16x16x32_bf16(af, bfrag[ch][0], acc0, 0, 0, 0);
        acc1 = __builtin_amdgcn_mfma_f32_16x16x32_bf16(af, bfrag[ch][1], acc1, 0, 0, 0);
    }

    // ---- S[w]: lanes m, m+16, m+32, m+48 hold quad-partials of same m ----
    Sp += __shfl_xor(Sp, 16, 64);
    Sp += __shfl_xor(Sp, 32, 64);
    if (lane < 16) s_S[wave * 16 + lane] = Sp;
    __syncthreads();   // also fences s_u reads before s_o aliasing below

    const float4 sr4 = *(const float4*)&s_S[wave * 16 + quad * 4];
    const float srv[4] = {sr4.x, sr4.y, sr4.z, sr4.w};

    // ---- Epilogue into LDS transpose buffer (aliases s_u) ----
    float* s_o = s_u;   // [k][w-local], stride 68
    #pragma unroll
    for (int r = 0; r < 4; ++r) {
        const int wl = wave * 16 + quad * 4 + r;         // D row -> w-local
        float d20 = srv[r] + pcol0 - 2.0f * acc0[r];
        s_o[l16 * 68 + wl] = -scale * sqrtf(fmaxf(d20, 0.f));
        if (l16 < 4) {
            float d21 = srv[r] + pcol1 - 2.0f * acc1[r];
            s_o[(16 + l16) * 68 + wl] = -scale * sqrtf(fmaxf(d21, 0.f));
        }
    }
    __syncthreads();

    // ---- Coalesced store: 20 k-rows x 64 w ----
    for (int i = tid; i < K * 16; i += 256) {
        const int k = i >> 4, g = i & 15;
        const float4 v = *(const float4*)&s_o[k * 68 + g * 4];
        *(float4*)(out + (size_t)(b * K + k) * HW + h * W + w0 + g * 4) = v;
    }
}

extern "C" void kernel_launch(void* const* d_in, const int* in_sizes, int n_in,
                              void* d_out, int out_size, void* d_ws, size_t ws_size,
                              hipStream_t stream) {
    const float* feats  = (const float*)d_in[0];
    const float* protos = (const float*)d_in[1];
    const float* dscale = (const float*)d_in[2];
    float* out = (float*)d_out;

    float* rn_ws    = (float*)d_ws;            // 32768 floats [b*H+h][c]
    float* ppsum_ws = rn_ws + 32768;           // 32 floats
    short* pnf_ws   = (short*)(ppsum_ws + 32); // 4096 bf16 fragment-packed

    isomax_prep<<<8193, 256, 0, stream>>>(feats, protos, rn_ws, pnf_ws, ppsum_ws);
    isomax_dist<<<B * H * 4, 256, 0, stream>>>(feats, rn_ws, pnf_ws, ppsum_ws,
                                               dscale, out);
}

// Round 7
// 86.819 us; speedup vs baseline: 1.1162x; 1.0543x over previous
//
#include <hip/hip_runtime.h>
#include <math.h>

// Problem dims (fixed by reference setup_inputs)
#define B 2
#define C 128
#define H 128
#define W 256
#define K 20
#define HW (H * W)
#define SO_STRIDE 260   // s_o row stride in floats (=4*65: float4-aligned, bank-skewed)

typedef float f32x4 __attribute__((ext_vector_type(4)));
typedef short bf16x8 __attribute__((ext_vector_type(8)));

// round-to-nearest-even fp32 -> bf16 bits (finite inputs)
__device__ __forceinline__ unsigned f2bf_bits(float x) {
    unsigned u = __float_as_uint(x);
    return (u + 0x7FFFu + ((u >> 16) & 1u)) >> 16;
}
__device__ __forceinline__ float bf_to_f(unsigned bits) {
    return __uint_as_float(bits << 16);
}

// One block per (b,h): 1024 threads = 16 waves; wave = 16-w m-tile (m0 = wave*16).
// No staging tile: A-fragments are read directly from global (L2-hot after the
// norm phase; 16 lanes share each 64B line). dist^2 = S + P - 2*dot, all bf16-
// consistent (S from the rounded values) => >= 0 exactly.
__global__ __launch_bounds__(1024) void isomax_fused(
    const float* __restrict__ feats, const float* __restrict__ protos,
    const float* __restrict__ dscale, float* __restrict__ out)
{
    __shared__ float s_rn[C];               // 1/max(||feats[b,c,h,:]||,eps)
    __shared__ float s_rp[32];              // proto inv-norms
    __shared__ float s_pp[32];              // sum_c bf(pn[k,c])^2
    __shared__ float s_S[W];                // S[w] = sum_c u[c,w]^2 (rounded u)
    __shared__ __align__(16) float s_o[K * SO_STRIDE];  // 20.8 KB output transpose

    const int tid  = threadIdx.x;
    const int wave = tid >> 6, lane = tid & 63;
    const int quad = lane >> 4, l16 = lane & 15;
    const int bh   = blockIdx.x;
    const int b    = bh >> 7, h = bh & 127;
    const int m0   = wave * 16;

    // ---- Phase P: prototype norms + ppsum (wave rd*16+wave handles one k) ----
    #pragma unroll
    for (int rd = 0; rd < 2; ++rd) {
        const int k = rd * 16 + wave;
        if (k < K) {
            const float* p = protos + k * C;
            const float a = p[lane], b2 = p[lane + 64];
            float ss = fmaf(a, a, b2 * b2);
            #pragma unroll
            for (int off = 32; off > 0; off >>= 1) ss += __shfl_xor(ss, off, 64);
            const float rp = 1.0f / fmaxf(sqrtf(ss), 1e-12f);
            const float q0 = bf_to_f(f2bf_bits(a * rp));
            const float q1 = bf_to_f(f2bf_bits(b2 * rp));
            float s2 = fmaf(q0, q0, q1 * q1);
            #pragma unroll
            for (int off = 32; off > 0; off >>= 1) s2 += __shfl_xor(s2, off, 64);
            if (lane == 0) { s_rp[k] = rp; s_pp[k] = s2; }
        }
    }

    // ---- Phase B: feature W-norms (the dim=1 quirk), R2-proven pattern ----
    for (int c = wave; c < C; c += 16) {
        const float* row = feats + ((size_t)((b * C + c) * H + h)) * W;
        const float4 v = ((const float4*)row)[lane];   // 64 lanes x float4 = full row
        float ss = fmaf(v.x, v.x, fmaf(v.y, v.y, fmaf(v.z, v.z, v.w * v.w)));
        #pragma unroll
        for (int off = 32; off > 0; off >>= 1) ss += __shfl_xor(ss, off, 64);
        if (lane == 0) s_rn[c] = 1.0f / fmaxf(sqrtf(ss), 1e-12f);
    }
    __syncthreads();   // s_rp, s_pp, s_rn ready

    // ---- B-fragments from L2-hot protos: bfrag[ch][t][j] = bf(pn[t*16+l16][ch*32+quad*8+j]) ----
    bf16x8 bfrag[4][2];
    #pragma unroll
    for (int t = 0; t < 2; ++t) {
        const int k = t * 16 + l16;
        const float rp = (k < K) ? s_rp[k] : 0.0f;
        #pragma unroll
        for (int ch = 0; ch < 4; ++ch) {
            bf16x8 f = {0, 0, 0, 0, 0, 0, 0, 0};
            if (k < K) {
                const float* pr = protos + k * C + ch * 32 + quad * 8;
                const float4 pa = *(const float4*)(pr);
                const float4 pb = *(const float4*)(pr + 4);
                f[0] = (short)f2bf_bits(pa.x * rp);
                f[1] = (short)f2bf_bits(pa.y * rp);
                f[2] = (short)f2bf_bits(pa.z * rp);
                f[3] = (short)f2bf_bits(pa.w * rp);
                f[4] = (short)f2bf_bits(pb.x * rp);
                f[5] = (short)f2bf_bits(pb.y * rp);
                f[6] = (short)f2bf_bits(pb.z * rp);
                f[7] = (short)f2bf_bits(pb.w * rp);
            }
            bfrag[ch][t] = f;
        }
    }

    // ---- Phase C: A-frags direct from global; 8 MFMAs; Sp from rounded u ----
    f32x4 acc0 = {0.f, 0.f, 0.f, 0.f}, acc1 = {0.f, 0.f, 0.f, 0.f};
    float Sp = 0.f;
    const float* fbase = feats + ((size_t)(b * C) * H + h) * W + m0 + l16;
    #pragma unroll
    for (int ch = 0; ch < 4; ++ch) {
        bf16x8 af;
        #pragma unroll
        for (int j = 0; j < 8; ++j) {
            const int c = ch * 32 + quad * 8 + j;
            const float uf = fbase[(size_t)c * HW] * s_rn[c];  // L2-hit, 16 lanes/line
            const unsigned bits = f2bf_bits(uf);
            af[j] = (short)bits;
            const float ur = bf_to_f(bits);
            Sp = fmaf(ur, ur, Sp);
        }
        acc0 = __builtin_amdgcn_mfma_f32_16x16x32_bf16(af, bfrag[ch][0], acc0, 0, 0, 0);
        acc1 = __builtin_amdgcn_mfma_f32_16x16x32_bf16(af, bfrag[ch][1], acc1, 0, 0, 0);
    }

    // ---- S[w]: sum quad-partials (lanes l16, l16+16, +32, +48), R5-proven ----
    Sp += __shfl_xor(Sp, 16, 64);
    Sp += __shfl_xor(Sp, 32, 64);
    if (lane < 16) s_S[m0 + lane] = Sp;
    __syncthreads();

    // ---- Epilogue into padded LDS transpose (R5-proven mapping) ----
    const float scale = fabsf(dscale[0]);
    const float pcol0 = s_pp[l16];
    const float pcol1 = (l16 < 4) ? s_pp[16 + l16] : 0.0f;
    #pragma unroll
    for (int r = 0; r < 4; ++r) {
        const int wl = m0 + quad * 4 + r;       // D row m = quad*4+r -> w
        const float Sm = s_S[wl];
        const float d20 = fmaxf(Sm + pcol0 - 2.0f * acc0[r], 0.f);
        s_o[l16 * SO_STRIDE + wl] = -scale * sqrtf(d20);
        if (l16 < 4) {
            const float d21 = fmaxf(Sm + pcol1 - 2.0f * acc1[r], 0.f);
            s_o[(16 + l16) * SO_STRIDE + wl] = -scale * sqrtf(d21);
        }
    }
    __syncthreads();

    // ---- Coalesced store: 20 k-rows x 256 w ----
    for (int i = tid; i < K * (W / 4); i += 1024) {
        const int k = i >> 6, g = i & 63;
        const float4 v = *(const float4*)&s_o[k * SO_STRIDE + g * 4];
        *(float4*)(out + ((size_t)(b * K + k)) * HW + h * W + g * 4) = v;
    }
}

extern "C" void kernel_launch(void* const* d_in, const int* in_sizes, int n_in,
                              void* d_out, int out_size, void* d_ws, size_t ws_size,
                              hipStream_t stream) {
    const float* feats  = (const float*)d_in[0];
    const float* protos = (const float*)d_in[1];
    const float* dscale = (const float*)d_in[2];
    float* out = (float*)d_out;

    isomax_fused<<<B * H, 1024, 0, stream>>>(feats, protos, dscale, out);
}